// Round 19
// baseline (107.159 us; speedup 1.0000x reference)
//
#include <hip/hip_runtime.h>

// B=32, F=node=128, T=2048, HID=256, NC=64, A=15 windows
// R18 + split accumulators (2-way) in syrk-main / op1 / op5 to double
// independent MFMA dependency chains in the latency-bound thin phases.

typedef float f32x4 __attribute__((ext_vector_type(4)));
typedef __bf16 bf16x8 __attribute__((ext_vector_type(8)));
typedef unsigned short u16x4 __attribute__((ext_vector_type(4)));
typedef unsigned short u16x8 __attribute__((ext_vector_type(8)));

__device__ inline unsigned short f2b(float f) {
  unsigned int u = __float_as_uint(f);
  unsigned int r = u + 0x7fffu + ((u >> 16) & 1u);
  return (unsigned short)(r >> 16);
}
__device__ inline float leaky(float v) { return v >= 0.f ? v : 0.2f * v; }

#define SWZ(k, r) ((k) ^ (((r) & 7) << 3))

// ---------------- k_front: W2T/W3T (20) + xw1 W1-in-LDS (256) + xT (2048) ----
__global__ __launch_bounds__(512) void k_front(const float* __restrict__ x,
                                               const float* __restrict__ W1,
                                               const float* __restrict__ W2,
                                               const float* __restrict__ W3,
                                               unsigned short* __restrict__ W2T,
                                               unsigned short* __restrict__ W3T,
                                               unsigned short* __restrict__ xT,
                                               unsigned short* __restrict__ XW1T) {
  __shared__ __align__(16) char lds[16640 + 8192 + 16384];  // tW | sW | sX[2]
  float (*tW)[65] = reinterpret_cast<float (*)[65]>(lds);
  unsigned short* sW = reinterpret_cast<unsigned short*>(lds + 16640);
  unsigned short (*sX)[64 * 64] =
      reinterpret_cast<unsigned short (*)[64 * 64]>(lds + 16640 + 8192);
  const int bid = blockIdx.x, tid = threadIdx.x;
  const int r = tid >> 3, c8 = (tid & 7) * 8;

  if (bid < 20) {
    const float* src;
    unsigned short* dst;
    int K, N, k0, n0;
    if (bid < 16) { src = W2; dst = W2T; K = 256; N = 256; k0 = (bid >> 2) * 64; n0 = (bid & 3) * 64; }
    else          { src = W3; dst = W3T; K = 256; N = 64;  k0 = (bid - 16) * 64; n0 = 0; }
#pragma unroll
    for (int j = 0; j < 8; ++j) tW[r][c8 + j] = src[(size_t)(k0 + r) * N + n0 + c8 + j];
    __syncthreads();
    u16x8 s;
#pragma unroll
    for (int j = 0; j < 8; ++j) s[j] = f2b(tW[c8 + j][r]);
    *(u16x8*)&dst[(size_t)(n0 + r) * K + k0 + c8] = s;
  } else if (bid < 276) {
    const int i = bid - 20;
    const int b = i >> 3, q = i & 7;
    const int hid0 = (q >> 1) * 64, f0 = (q & 1) * 64;
    const int w = tid >> 6, lane = tid & 63;
    const int l15 = lane & 15, l4 = lane >> 4;
    const float* xb = x + ((size_t)b * 128 + f0) * 2048;
    f32x4 xr0, xr1, wr0, wr1;
    f32x4 acc[2] = {};

    auto LOADX = [&](int kb) {
      xr0 = *(const f32x4*)&xb[(size_t)r * 2048 + kb * 64 + c8];
      xr1 = *(const f32x4*)&xb[(size_t)r * 2048 + kb * 64 + c8 + 4];
    };
    auto LOADW = [&](int kb) {
      wr0 = *(const f32x4*)&W1[(size_t)(kb * 64 + r) * 256 + hid0 + c8];
      wr1 = *(const f32x4*)&W1[(size_t)(kb * 64 + r) * 256 + hid0 + c8 + 4];
    };
    auto STOREX = [&](int buf) {
      u16x8 s;
#pragma unroll
      for (int j = 0; j < 8; ++j) s[j] = f2b(j < 4 ? xr0[j] : xr1[j - 4]);
      *(u16x8*)&sX[buf][r * 64 + SWZ(c8, r)] = s;
    };
    auto STOREW = [&]() {
#pragma unroll
      for (int j = 0; j < 4; ++j) { tW[r][c8 + j] = wr0[j]; tW[r][c8 + 4 + j] = wr1[j]; }
    };
    auto PACKW = [&]() {
      u16x8 s;
#pragma unroll
      for (int j = 0; j < 8; ++j) s[j] = f2b(tW[c8 + j][r]);
      *(u16x8*)&sW[r * 64 + SWZ(c8, r)] = s;
    };

    LOADX(0); LOADW(0);
    STOREX(0); STOREW();
    __syncthreads();
    PACKW();
    __syncthreads();
    for (int kb = 0; kb < 32; ++kb) {
      if (kb < 31) { LOADX(kb + 1); LOADW(kb + 1); }
      const int buf = kb & 1;
#pragma unroll
      for (int ks = 0; ks < 2; ++ks) {
        int ar = (w & 3) * 16 + l15;
        bf16x8 af = *(const bf16x8*)&sW[ar * 64 + SWZ(ks * 32 + l4 * 8, ar)];
#pragma unroll
        for (int nt = 0; nt < 2; ++nt) {
          int br = (w >> 2) * 32 + nt * 16 + l15;
          bf16x8 bf = *(const bf16x8*)&sX[buf][br * 64 + SWZ(ks * 32 + l4 * 8, br)];
          acc[nt] = __builtin_amdgcn_mfma_f32_16x16x32_bf16(af, bf, acc[nt], 0, 0, 0);
        }
      }
      if (kb < 31) {
        STOREX(buf ^ 1);
        STOREW();
        __syncthreads();
        PACKW();
        __syncthreads();
      }
    }
    unsigned short* dst = XW1T + (size_t)b * 256 * 128;
#pragma unroll
    for (int nt = 0; nt < 2; ++nt)
#pragma unroll
      for (int rr = 0; rr < 4; ++rr) {
        int p = hid0 + (w & 3) * 16 + l4 * 4 + rr;
        int f = f0 + (w >> 2) * 32 + nt * 16 + l15;
        dst[p * 128 + f] = f2b(acc[nt][rr]);
      }
  } else {
    const int i = bid - 276;
    const int b = i >> 6, rem = i & 63;
    const int t0 = (rem >> 1) * 64, f0 = (rem & 1) * 64;
    const float* xb = x + ((size_t)b * 128 + f0) * 2048 + t0;
    f32x4 v0 = *(const f32x4*)&xb[(size_t)r * 2048 + c8];
    f32x4 v1 = *(const f32x4*)&xb[(size_t)r * 2048 + c8 + 4];
#pragma unroll
    for (int j = 0; j < 4; ++j) { tW[r][c8 + j] = v0[j]; tW[r][c8 + 4 + j] = v1[j]; }
    __syncthreads();
    u16x8 s;
#pragma unroll
    for (int j = 0; j < 8; ++j) s[j] = f2b(tW[c8 + j][r]);
    *(u16x8*)&xT[((size_t)b * 2048 + t0 + r) * 128 + f0 + c8] = s;
  }
}

// ---------------- k_chain: paired windows (i, i+240), 240 blocks ----------------
__global__ __launch_bounds__(512, 2) void k_chain(
    const unsigned short* __restrict__ xT, const unsigned short* __restrict__ XW1T,
    const unsigned short* __restrict__ W2T, const unsigned short* __restrict__ W3T,
    const float* __restrict__ b1g, const float* __restrict__ b2g,
    const float* __restrict__ b3g, float* __restrict__ gXa) {
  __shared__ __align__(16) unsigned short R0[2][128 * 128];  // 64 KB
  __shared__ __align__(16) unsigned short R1[2][128 * 128];  // 64 KB
  __shared__ float fS[2][256];                               // 2 KB

  const int tid = threadIdx.x;
  const int w = tid >> 6, lane = tid & 63;
  const int l15 = lane & 15, l4 = lane >> 4;
  const int pid = (blockIdx.x & 7) * 30 + (blockIdx.x >> 3);  // 240 = 8*30
  int bb[2], aa[2];
  bb[0] = pid / 15;         aa[0] = pid % 15;
  bb[1] = (pid + 240) / 15; aa[1] = (pid + 240) % 15;
  const int m0 = w * 16;
  const float inv128 = 1.f / 128.f;

  // ---- P0: win loads for both windows ----
#pragma unroll
  for (int v = 0; v < 2; ++v) {
    const unsigned short* src = xT + ((size_t)bb[v] * 2048 + (size_t)aa[v] * 128) * 128;
#pragma unroll 1
    for (int it = 0; it < 4; ++it) {
      int tt = tid + it * 512;
      int j = tt >> 4, f8 = (tt & 15) * 8;
      *(u16x8*)&R1[v][j * 128 + SWZ(f8, j)] = *(const u16x8*)&src[j * 128 + f8];
    }
  }
  __syncthreads();  // B0

  // ---- syrk prologue (both) ----
  bf16x8 afw[2][4];
  f32x4 sacc[2], dacc[2];
  bf16x8 ones;
#pragma unroll
  for (int q = 0; q < 8; ++q) ones[q] = (__bf16)1.0f;
#pragma unroll
  for (int v = 0; v < 2; ++v) {
#pragma unroll
    for (int ks = 0; ks < 4; ++ks) {
      int ar = m0 + l15;
      afw[v][ks] = *(const bf16x8*)&R1[v][ar * 128 + SWZ(ks * 32 + l4 * 8, ar)];
    }
    sacc[v] = f32x4{0.f, 0.f, 0.f, 0.f};
    dacc[v] = f32x4{0.f, 0.f, 0.f, 0.f};
#pragma unroll
    for (int ks = 0; ks < 4; ++ks) {
      sacc[v] = __builtin_amdgcn_mfma_f32_16x16x32_bf16(afw[v][ks], ones, sacc[v], 0, 0, 0);
      dacc[v] = __builtin_amdgcn_mfma_f32_16x16x32_bf16(afw[v][ks], afw[v][ks], dacc[v], 0, 0, 0);
    }
#pragma unroll
    for (int r = 0; r < 4; ++r) {
      if (l15 == 0) fS[v][m0 + l4 * 4 + r] = sacc[v][r];
      if (l15 == l4 * 4 + r)
        fS[v][128 + m0 + l4 * 4 + r] = dacc[v][r] - sacc[v][r] * sacc[v][r] * inv128;
    }
  }
  __syncthreads();  // B1

  // ---- syrk main (interleaved per nt, split acc) -> adj transposed store ----
  float div_[2][4];
#pragma unroll
  for (int v = 0; v < 2; ++v)
#pragma unroll
    for (int r = 0; r < 4; ++r) {
      float d = fS[v][128 + m0 + l4 * 4 + r];
      div_[v][r] = d > 0.f ? __frsqrt_rn(d) : 0.f;
    }
#pragma unroll 1
  for (int nt = 0; nt < 8; ++nt) {
    int col = nt * 16 + l15;
#pragma unroll
    for (int v = 0; v < 2; ++v) {
      f32x4 c0 = {}, c1 = {};
#pragma unroll
      for (int ks = 0; ks < 2; ++ks) {
        bf16x8 bf0 = *(const bf16x8*)&R1[v][col * 128 + SWZ(ks * 32 + l4 * 8, col)];
        bf16x8 bf1 = *(const bf16x8*)&R1[v][col * 128 + SWZ((ks + 2) * 32 + l4 * 8, col)];
        c0 = __builtin_amdgcn_mfma_f32_16x16x32_bf16(afw[v][ks], bf0, c0, 0, 0, 0);
        c1 = __builtin_amdgcn_mfma_f32_16x16x32_bf16(afw[v][ks + 2], bf1, c1, 0, 0, 0);
      }
      f32x4 c = c0 + c1;
      float fc = fS[v][col];
      float dc = fS[v][128 + col];
      float djv = dc > 0.f ? __frsqrt_rn(dc) : 0.f;
      u16x4 pk;
#pragma unroll
      for (int r = 0; r < 4; ++r) {
        float val = (c[r] - sacc[v][r] * fc * inv128) * div_[v][r] * djv;
        val = fminf(1.f, fmaxf(-1.f, val));
        val = 0.5f * val + 0.5f;
        if (div_[v][r] == 0.f || djv == 0.f) val = 0.f;  // nan_to_num
        pk[r] = f2b(val);
      }
      *(u16x4*)&R0[v][col * 128 + SWZ(m0 + l4 * 4, col)] = pk;
    }
  }
  __syncthreads();  // B2: adj complete (both)

  bf16x8 afj[2][4];
#pragma unroll
  for (int v = 0; v < 2; ++v)
#pragma unroll
    for (int ks = 0; ks < 4; ++ks)
      afj[v][ks] = *(const bf16x8*)&R0[v][(m0 + l15) * 128 + SWZ(ks * 32 + l4 * 8, m0 + l15)];
  // afj/op1 writes touch only this wave's own rows -> no barrier (R12-proven)

  // ---- op1: h1 = leaky(adj @ XW1b + b1), interleaved, B prefetched, split acc ----
  const unsigned short* XWb0 = XW1T + (size_t)bb[0] * 256 * 128;
  const unsigned short* XWb1 = XW1T + (size_t)bb[1] * 256 * 128;
#pragma unroll 1
  for (int half = 0; half < 2; ++half) {
    const unsigned short* Bb0 = XWb0 + (size_t)half * 128 * 128 + l4 * 8;
    const unsigned short* Bb1 = XWb1 + (size_t)half * 128 * 128 + l4 * 8;
    bf16x8 bpf[2][4];
#pragma unroll
    for (int ks = 0; ks < 4; ++ks) {
      bpf[0][ks] = *(const bf16x8*)&Bb0[(size_t)l15 * 128 + ks * 32];
      bpf[1][ks] = *(const bf16x8*)&Bb1[(size_t)l15 * 128 + ks * 32];
    }
#pragma unroll 1
    for (int nt = 0; nt < 8; ++nt) {
      float bias = b1g[half * 128 + nt * 16 + l15];
#pragma unroll
      for (int v = 0; v < 2; ++v) {
        bf16x8 bc[4];
#pragma unroll
        for (int ks = 0; ks < 4; ++ks) bc[ks] = bpf[v][ks];
        if (nt < 7) {
          const unsigned short* Bn = (v ? Bb1 : Bb0) + (size_t)((nt + 1) * 16 + l15) * 128;
#pragma unroll
          for (int ks = 0; ks < 4; ++ks) bpf[v][ks] = *(const bf16x8*)&Bn[ks * 32];
        }
        f32x4 a0 = {}, a1 = {};
        a0 = __builtin_amdgcn_mfma_f32_16x16x32_bf16(afj[v][0], bc[0], a0, 0, 0, 0);
        a1 = __builtin_amdgcn_mfma_f32_16x16x32_bf16(afj[v][1], bc[1], a1, 0, 0, 0);
        a0 = __builtin_amdgcn_mfma_f32_16x16x32_bf16(afj[v][2], bc[2], a0, 0, 0, 0);
        a1 = __builtin_amdgcn_mfma_f32_16x16x32_bf16(afj[v][3], bc[3], a1, 0, 0, 0);
        f32x4 acc = a0 + a1;
        unsigned short* Rd = half ? R0[v] : R1[v];
#pragma unroll
        for (int r = 0; r < 4; ++r) {
          int row = m0 + l4 * 4 + r;
          Rd[row * 128 + SWZ(nt * 16 + l15, row)] = f2b(leaky(acc[r] + bias));
        }
      }
    }
  }
  __syncthreads();  // B3: h1 complete (both)

  // ---- op2: u2T = W2T @ h1^T, K=256; A shared + prefetched 1 ks ahead ----
  f32x4 u2[2][2][8] = {};
  {
    const unsigned short* A0 = &W2T[(size_t)(w * 32 + l15) * 256 + l4 * 8];
    const unsigned short* A1 = &W2T[(size_t)(w * 32 + 16 + l15) * 256 + l4 * 8];
    bf16x8 a0p = *(const bf16x8*)&A0[0];
    bf16x8 a1p = *(const bf16x8*)&A1[0];
#pragma unroll 1
    for (int ks = 0; ks < 8; ++ks) {
      bf16x8 a0 = a0p, a1 = a1p;
      if (ks < 7) {
        a0p = *(const bf16x8*)&A0[(ks + 1) * 32];
        a1p = *(const bf16x8*)&A1[(ks + 1) * 32];
      }
      int kk = (ks & 3) * 32 + l4 * 8;
#pragma unroll
      for (int v = 0; v < 2; ++v) {
        const unsigned short* Rs = (ks < 4) ? R1[v] : R0[v];
#pragma unroll
        for (int nt = 0; nt < 8; ++nt) {
          int br = nt * 16 + l15;
          bf16x8 bf = *(const bf16x8*)&Rs[br * 128 + SWZ(kk, br)];
          u2[v][0][nt] = __builtin_amdgcn_mfma_f32_16x16x32_bf16(a0, bf, u2[v][0][nt], 0, 0, 0);
          u2[v][1][nt] = __builtin_amdgcn_mfma_f32_16x16x32_bf16(a1, bf, u2[v][1][nt], 0, 0, 0);
        }
      }
    }
  }
  __syncthreads();  // B4: h1 reads done (both)

#pragma unroll
  for (int v = 0; v < 2; ++v)
#pragma unroll
    for (int mt = 0; mt < 2; ++mt)
#pragma unroll
      for (int nt = 0; nt < 8; ++nt)
#pragma unroll
        for (int r = 0; r < 4; ++r) {
          int grow = w * 32 + mt * 16 + l4 * 4 + r;
          int col = nt * 16 + l15;
          unsigned short* Rd = (grow < 128) ? R0[v] : R1[v];
          int lr = grow & 127;
          Rd[lr * 128 + SWZ(col, lr)] = f2b(u2[v][mt][nt][r]);
        }
  __syncthreads();  // B5: u2T stored

  // ---- op3: h2 = leaky(adj @ u2 + b2), full hid 256, interleaved ----
  f32x4 h2[2][16];
#pragma unroll
  for (int v = 0; v < 2; ++v)
#pragma unroll
    for (int nt = 0; nt < 16; ++nt) h2[v][nt] = f32x4{0.f, 0.f, 0.f, 0.f};
#pragma unroll
  for (int ks = 0; ks < 4; ++ks)
#pragma unroll
    for (int nt = 0; nt < 16; ++nt) {
      int brl = (nt & 7) * 16 + l15;
#pragma unroll
      for (int v = 0; v < 2; ++v) {
        const unsigned short* Rs = (nt < 8) ? R0[v] : R1[v];
        bf16x8 bf = *(const bf16x8*)&Rs[brl * 128 + SWZ(ks * 32 + l4 * 8, brl)];
        h2[v][nt] = __builtin_amdgcn_mfma_f32_16x16x32_bf16(afj[v][ks], bf, h2[v][nt], 0, 0, 0);
      }
    }
  __syncthreads();  // B6: u2T reads done

#pragma unroll
  for (int v = 0; v < 2; ++v)
#pragma unroll
    for (int nt = 0; nt < 16; ++nt) {
      float bias = b2g[nt * 16 + l15];
#pragma unroll
      for (int r = 0; r < 4; ++r) {
        int row = m0 + l4 * 4 + r;
        int coll = (nt & 7) * 16 + l15;
        unsigned short* Rd = (nt < 8) ? R0[v] : R1[v];
        Rd[row * 128 + SWZ(coll, row)] = f2b(leaky(h2[v][nt][r] + bias));
      }
    }
  // ---- hoist op4 A-frags (shared across pair) ----
  const int mrow = (w >> 1) * 16, ntb = (w & 1) * 4;
  bf16x8 a3f[8];
#pragma unroll
  for (int ks = 0; ks < 8; ++ks)
    a3f[ks] = *(const bf16x8*)&W3T[(size_t)(mrow + l15) * 256 + ks * 32 + l4 * 8];
  __syncthreads();  // B7: h2 stored

  // ---- op4: u3T = W3T @ h2^T, K=256, interleaved ----
  f32x4 u3[2][4] = {};
#pragma unroll
  for (int kh = 0; kh < 2; ++kh) {
#pragma unroll
    for (int ks = 0; ks < 4; ++ks) {
#pragma unroll
      for (int nti = 0; nti < 4; ++nti) {
        int br = (ntb + nti) * 16 + l15;
#pragma unroll
        for (int v = 0; v < 2; ++v) {
          const unsigned short* Rs = kh ? R1[v] : R0[v];
          bf16x8 bf = *(const bf16x8*)&Rs[br * 128 + SWZ(ks * 32 + l4 * 8, br)];
          u3[v][nti] = __builtin_amdgcn_mfma_f32_16x16x32_bf16(a3f[kh * 4 + ks], bf, u3[v][nti], 0, 0, 0);
        }
      }
    }
  }
  __syncthreads();  // B8: h2 reads done

#pragma unroll
  for (int v = 0; v < 2; ++v)
#pragma unroll
    for (int nti = 0; nti < 4; ++nti)
#pragma unroll
      for (int r = 0; r < 4; ++r) {
        int grow = mrow + l4 * 4 + r;
        int col = (ntb + nti) * 16 + l15;
        R0[v][grow * 128 + SWZ(col, grow)] = f2b(u3[v][nti][r]);
      }
  __syncthreads();  // B9: u3T stored

  // ---- op5: xa = leaky(adj @ u3 + b3); mean via shuffles, split acc ----
#pragma unroll 1
  for (int nt = 0; nt < 4; ++nt) {
    int br = nt * 16 + l15;
    float bias = b3g[br];
#pragma unroll
    for (int v = 0; v < 2; ++v) {
      f32x4 a0 = {}, a1 = {};
#pragma unroll
      for (int ks = 0; ks < 2; ++ks) {
        bf16x8 bf0 = *(const bf16x8*)&R0[v][br * 128 + SWZ(ks * 32 + l4 * 8, br)];
        bf16x8 bf1 = *(const bf16x8*)&R0[v][br * 128 + SWZ((ks + 2) * 32 + l4 * 8, br)];
        a0 = __builtin_amdgcn_mfma_f32_16x16x32_bf16(afj[v][ks], bf0, a0, 0, 0, 0);
        a1 = __builtin_amdgcn_mfma_f32_16x16x32_bf16(afj[v][ks + 2], bf1, a1, 0, 0, 0);
      }
      f32x4 acc = a0 + a1;
      float s = 0.f;
#pragma unroll
      for (int r = 0; r < 4; ++r) s += leaky(acc[r] + bias);
      s += __shfl_xor(s, 16);
      s += __shfl_xor(s, 32);
      if (l4 == 0) reinterpret_cast<float*>(R1[v])[w * 64 + br] = s;
    }
  }
  __syncthreads();  // B10
  if (tid < 128) {
    int v = tid >> 6, c = tid & 63;
    const float* pf = reinterpret_cast<const float*>(R1[v]);
    float s = 0.f;
#pragma unroll
    for (int gg = 0; gg < 8; ++gg) s += pf[gg * 64 + c];
    gXa[((size_t)bb[v] * 15 + aa[v]) * 64 + c] = s * inv128;
  }
}

// ---------------- k_head: per-batch head ----------------
__global__ __launch_bounds__(256) void k_head(const float* __restrict__ gXa,
                                              const float* __restrict__ W4,
                                              const float* __restrict__ b4,
                                              float* __restrict__ out) {
  __shared__ float xb[15 * 64];
  __shared__ float c2[15 * 16];
  __shared__ float mu[15];
  __shared__ float dinv[15];
  __shared__ float yy[15 * 64];
  __shared__ float zz[15 * 64];
  const int b = blockIdx.x;
  const int tid = threadIdx.x;
  for (int e = tid; e < 960; e += 256) xb[e] = gXa[(size_t)b * 960 + e];
  __syncthreads();
  if (tid < 15) {
    float s = 0.f;
    for (int c = 0; c < 64; ++c) s += xb[tid * 64 + c];
    mu[tid] = s * (1.f / 64.f);
  }
  __syncthreads();
  if (tid < 225) {
    int p = tid / 15, q = tid % 15;
    float s = 0.f;
    for (int c = 0; c < 64; ++c)
      s += (xb[p * 64 + c] - mu[p]) * (xb[q * 64 + c] - mu[q]);
    c2[p * 16 + q] = s;
  }
  __syncthreads();
  if (tid < 15) {
    float d = c2[tid * 16 + tid];
    dinv[tid] = d > 0.f ? (1.f / sqrtf(d)) : 0.f;
  }
  __syncthreads();
  if (tid < 225) {
    int p = tid / 15, q = tid % 15;
    float v = c2[p * 16 + q] * dinv[p] * dinv[q];
    v = fminf(1.f, fmaxf(-1.f, v));
    if (dinv[p] == 0.f || dinv[q] == 0.f) v = 0.f;
    c2[p * 16 + q] = v;
  }
  __syncthreads();
  for (int e = tid; e < 960; e += 256) {
    int p = e >> 6, c = e & 63;
    float s = 0.f;
    for (int q = 0; q < 15; ++q) s += c2[p * 16 + q] * xb[q * 64 + c];
    yy[e] = s;
  }
  __syncthreads();
  for (int e = tid; e < 960; e += 256) {
    int p = e >> 6, c = e & 63;
    float s = b4[c];
    for (int k = 0; k < 64; ++k) s += yy[p * 64 + k] * W4[k * 64 + c];
    zz[e] = leaky(s);
  }
  __syncthreads();
  if (tid < 64) {
    float m = -INFINITY;
    for (int p = 0; p < 15; ++p) m = fmaxf(m, zz[p * 64 + tid]);
    out[(size_t)b * 64 + tid] = m;
  }
}

extern "C" void kernel_launch(void* const* d_in, const int* in_sizes, int n_in,
                              void* d_out, int out_size, void* d_ws, size_t ws_size,
                              hipStream_t stream) {
  const float* x  = (const float*)d_in[0];
  const float* W1 = (const float*)d_in[1];
  const float* b1 = (const float*)d_in[2];
  const float* W2 = (const float*)d_in[3];
  const float* b2 = (const float*)d_in[4];
  const float* W3 = (const float*)d_in[5];
  const float* b3 = (const float*)d_in[6];
  const float* W4 = (const float*)d_in[7];
  const float* b4 = (const float*)d_in[8];
  float* out = (float*)d_out;

  char* ws = (char*)d_ws;
  unsigned short* xT   = (unsigned short*)ws;                 // 16 MB
  unsigned short* XW1T = (unsigned short*)(ws + 16777216);    // 2 MB
  unsigned short* W2T  = (unsigned short*)(ws + 18874368);    // 128 KB
  unsigned short* W3T  = (unsigned short*)(ws + 19005440);    // 32 KB
  float* gXa           = (float*)(ws + 19038208);             // 120 KB

  k_front<<<2324, 512, 0, stream>>>(x, W1, W2, W3, W2T, W3T, xT, XW1T);
  k_chain<<<240, 512, 0, stream>>>(xT, XW1T, W2T, W3T, b1, b2, b3, gXa);
  k_head<<<32, 256, 0, stream>>>(gXa, W4, b4, out);
}

// Round 20
// 106.769 us; speedup vs baseline: 1.0037x; 1.0037x over previous
//
#include <hip/hip_runtime.h>

// B=32, F=node=128, T=2048, HID=256, NC=64, A=15 windows
// FINAL (consolidated best = R18, 106.8 µs):
// k_front (W2T/W3T + W1-in-LDS xw1 + xT) -> k_chain (paired windows,
// op1 B-prefetch + op2 A-prefetch) -> k_head.

typedef float f32x4 __attribute__((ext_vector_type(4)));
typedef __bf16 bf16x8 __attribute__((ext_vector_type(8)));
typedef unsigned short u16x4 __attribute__((ext_vector_type(4)));
typedef unsigned short u16x8 __attribute__((ext_vector_type(8)));

__device__ inline unsigned short f2b(float f) {
  unsigned int u = __float_as_uint(f);
  unsigned int r = u + 0x7fffu + ((u >> 16) & 1u);
  return (unsigned short)(r >> 16);
}
__device__ inline float leaky(float v) { return v >= 0.f ? v : 0.2f * v; }

#define SWZ(k, r) ((k) ^ (((r) & 7) << 3))

// ---------------- k_front: W2T/W3T (20) + xw1 W1-in-LDS (256) + xT (2048) ----
__global__ __launch_bounds__(512) void k_front(const float* __restrict__ x,
                                               const float* __restrict__ W1,
                                               const float* __restrict__ W2,
                                               const float* __restrict__ W3,
                                               unsigned short* __restrict__ W2T,
                                               unsigned short* __restrict__ W3T,
                                               unsigned short* __restrict__ xT,
                                               unsigned short* __restrict__ XW1T) {
  __shared__ __align__(16) char lds[16640 + 8192 + 16384];  // tW | sW | sX[2]
  float (*tW)[65] = reinterpret_cast<float (*)[65]>(lds);
  unsigned short* sW = reinterpret_cast<unsigned short*>(lds + 16640);
  unsigned short (*sX)[64 * 64] =
      reinterpret_cast<unsigned short (*)[64 * 64]>(lds + 16640 + 8192);
  const int bid = blockIdx.x, tid = threadIdx.x;
  const int r = tid >> 3, c8 = (tid & 7) * 8;

  if (bid < 20) {
    const float* src;
    unsigned short* dst;
    int K, N, k0, n0;
    if (bid < 16) { src = W2; dst = W2T; K = 256; N = 256; k0 = (bid >> 2) * 64; n0 = (bid & 3) * 64; }
    else          { src = W3; dst = W3T; K = 256; N = 64;  k0 = (bid - 16) * 64; n0 = 0; }
#pragma unroll
    for (int j = 0; j < 8; ++j) tW[r][c8 + j] = src[(size_t)(k0 + r) * N + n0 + c8 + j];
    __syncthreads();
    u16x8 s;
#pragma unroll
    for (int j = 0; j < 8; ++j) s[j] = f2b(tW[c8 + j][r]);
    *(u16x8*)&dst[(size_t)(n0 + r) * K + k0 + c8] = s;
  } else if (bid < 276) {
    const int i = bid - 20;
    const int b = i >> 3, q = i & 7;
    const int hid0 = (q >> 1) * 64, f0 = (q & 1) * 64;
    const int w = tid >> 6, lane = tid & 63;
    const int l15 = lane & 15, l4 = lane >> 4;
    const float* xb = x + ((size_t)b * 128 + f0) * 2048;
    f32x4 xr0, xr1, wr0, wr1;
    f32x4 acc[2] = {};

    auto LOADX = [&](int kb) {
      xr0 = *(const f32x4*)&xb[(size_t)r * 2048 + kb * 64 + c8];
      xr1 = *(const f32x4*)&xb[(size_t)r * 2048 + kb * 64 + c8 + 4];
    };
    auto LOADW = [&](int kb) {
      wr0 = *(const f32x4*)&W1[(size_t)(kb * 64 + r) * 256 + hid0 + c8];
      wr1 = *(const f32x4*)&W1[(size_t)(kb * 64 + r) * 256 + hid0 + c8 + 4];
    };
    auto STOREX = [&](int buf) {
      u16x8 s;
#pragma unroll
      for (int j = 0; j < 8; ++j) s[j] = f2b(j < 4 ? xr0[j] : xr1[j - 4]);
      *(u16x8*)&sX[buf][r * 64 + SWZ(c8, r)] = s;
    };
    auto STOREW = [&]() {
#pragma unroll
      for (int j = 0; j < 4; ++j) { tW[r][c8 + j] = wr0[j]; tW[r][c8 + 4 + j] = wr1[j]; }
    };
    auto PACKW = [&]() {
      u16x8 s;
#pragma unroll
      for (int j = 0; j < 8; ++j) s[j] = f2b(tW[c8 + j][r]);
      *(u16x8*)&sW[r * 64 + SWZ(c8, r)] = s;
    };

    LOADX(0); LOADW(0);
    STOREX(0); STOREW();
    __syncthreads();
    PACKW();
    __syncthreads();
    for (int kb = 0; kb < 32; ++kb) {
      if (kb < 31) { LOADX(kb + 1); LOADW(kb + 1); }
      const int buf = kb & 1;
#pragma unroll
      for (int ks = 0; ks < 2; ++ks) {
        int ar = (w & 3) * 16 + l15;
        bf16x8 af = *(const bf16x8*)&sW[ar * 64 + SWZ(ks * 32 + l4 * 8, ar)];
#pragma unroll
        for (int nt = 0; nt < 2; ++nt) {
          int br = (w >> 2) * 32 + nt * 16 + l15;
          bf16x8 bf = *(const bf16x8*)&sX[buf][br * 64 + SWZ(ks * 32 + l4 * 8, br)];
          acc[nt] = __builtin_amdgcn_mfma_f32_16x16x32_bf16(af, bf, acc[nt], 0, 0, 0);
        }
      }
      if (kb < 31) {
        STOREX(buf ^ 1);
        STOREW();
        __syncthreads();
        PACKW();
        __syncthreads();
      }
    }
    unsigned short* dst = XW1T + (size_t)b * 256 * 128;
#pragma unroll
    for (int nt = 0; nt < 2; ++nt)
#pragma unroll
      for (int rr = 0; rr < 4; ++rr) {
        int p = hid0 + (w & 3) * 16 + l4 * 4 + rr;
        int f = f0 + (w >> 2) * 32 + nt * 16 + l15;
        dst[p * 128 + f] = f2b(acc[nt][rr]);
      }
  } else {
    const int i = bid - 276;
    const int b = i >> 6, rem = i & 63;
    const int t0 = (rem >> 1) * 64, f0 = (rem & 1) * 64;
    const float* xb = x + ((size_t)b * 128 + f0) * 2048 + t0;
    f32x4 v0 = *(const f32x4*)&xb[(size_t)r * 2048 + c8];
    f32x4 v1 = *(const f32x4*)&xb[(size_t)r * 2048 + c8 + 4];
#pragma unroll
    for (int j = 0; j < 4; ++j) { tW[r][c8 + j] = v0[j]; tW[r][c8 + 4 + j] = v1[j]; }
    __syncthreads();
    u16x8 s;
#pragma unroll
    for (int j = 0; j < 8; ++j) s[j] = f2b(tW[c8 + j][r]);
    *(u16x8*)&xT[((size_t)b * 2048 + t0 + r) * 128 + f0 + c8] = s;
  }
}

// ---------------- k_chain: paired windows (i, i+240), 240 blocks ----------------
__global__ __launch_bounds__(512, 2) void k_chain(
    const unsigned short* __restrict__ xT, const unsigned short* __restrict__ XW1T,
    const unsigned short* __restrict__ W2T, const unsigned short* __restrict__ W3T,
    const float* __restrict__ b1g, const float* __restrict__ b2g,
    const float* __restrict__ b3g, float* __restrict__ gXa) {
  __shared__ __align__(16) unsigned short R0[2][128 * 128];  // 64 KB
  __shared__ __align__(16) unsigned short R1[2][128 * 128];  // 64 KB
  __shared__ float fS[2][256];                               // 2 KB

  const int tid = threadIdx.x;
  const int w = tid >> 6, lane = tid & 63;
  const int l15 = lane & 15, l4 = lane >> 4;
  const int pid = (blockIdx.x & 7) * 30 + (blockIdx.x >> 3);  // 240 = 8*30
  int bb[2], aa[2];
  bb[0] = pid / 15;         aa[0] = pid % 15;
  bb[1] = (pid + 240) / 15; aa[1] = (pid + 240) % 15;
  const int m0 = w * 16;
  const float inv128 = 1.f / 128.f;

  // ---- P0: win loads for both windows ----
#pragma unroll
  for (int v = 0; v < 2; ++v) {
    const unsigned short* src = xT + ((size_t)bb[v] * 2048 + (size_t)aa[v] * 128) * 128;
#pragma unroll 1
    for (int it = 0; it < 4; ++it) {
      int tt = tid + it * 512;
      int j = tt >> 4, f8 = (tt & 15) * 8;
      *(u16x8*)&R1[v][j * 128 + SWZ(f8, j)] = *(const u16x8*)&src[j * 128 + f8];
    }
  }
  __syncthreads();  // B0

  // ---- syrk prologue (both) ----
  bf16x8 afw[2][4];
  f32x4 sacc[2], dacc[2];
  bf16x8 ones;
#pragma unroll
  for (int q = 0; q < 8; ++q) ones[q] = (__bf16)1.0f;
#pragma unroll
  for (int v = 0; v < 2; ++v) {
#pragma unroll
    for (int ks = 0; ks < 4; ++ks) {
      int ar = m0 + l15;
      afw[v][ks] = *(const bf16x8*)&R1[v][ar * 128 + SWZ(ks * 32 + l4 * 8, ar)];
    }
    sacc[v] = f32x4{0.f, 0.f, 0.f, 0.f};
    dacc[v] = f32x4{0.f, 0.f, 0.f, 0.f};
#pragma unroll
    for (int ks = 0; ks < 4; ++ks) {
      sacc[v] = __builtin_amdgcn_mfma_f32_16x16x32_bf16(afw[v][ks], ones, sacc[v], 0, 0, 0);
      dacc[v] = __builtin_amdgcn_mfma_f32_16x16x32_bf16(afw[v][ks], afw[v][ks], dacc[v], 0, 0, 0);
    }
#pragma unroll
    for (int r = 0; r < 4; ++r) {
      if (l15 == 0) fS[v][m0 + l4 * 4 + r] = sacc[v][r];
      if (l15 == l4 * 4 + r)
        fS[v][128 + m0 + l4 * 4 + r] = dacc[v][r] - sacc[v][r] * sacc[v][r] * inv128;
    }
  }
  __syncthreads();  // B1

  // ---- syrk main (interleaved per nt) -> adj transposed store ----
  float div_[2][4];
#pragma unroll
  for (int v = 0; v < 2; ++v)
#pragma unroll
    for (int r = 0; r < 4; ++r) {
      float d = fS[v][128 + m0 + l4 * 4 + r];
      div_[v][r] = d > 0.f ? __frsqrt_rn(d) : 0.f;
    }
#pragma unroll 1
  for (int nt = 0; nt < 8; ++nt) {
    int col = nt * 16 + l15;
#pragma unroll
    for (int v = 0; v < 2; ++v) {
      f32x4 c = {};
#pragma unroll
      for (int ks = 0; ks < 4; ++ks) {
        bf16x8 bf = *(const bf16x8*)&R1[v][col * 128 + SWZ(ks * 32 + l4 * 8, col)];
        c = __builtin_amdgcn_mfma_f32_16x16x32_bf16(afw[v][ks], bf, c, 0, 0, 0);
      }
      float fc = fS[v][col];
      float dc = fS[v][128 + col];
      float djv = dc > 0.f ? __frsqrt_rn(dc) : 0.f;
      u16x4 pk;
#pragma unroll
      for (int r = 0; r < 4; ++r) {
        float val = (c[r] - sacc[v][r] * fc * inv128) * div_[v][r] * djv;
        val = fminf(1.f, fmaxf(-1.f, val));
        val = 0.5f * val + 0.5f;
        if (div_[v][r] == 0.f || djv == 0.f) val = 0.f;  // nan_to_num
        pk[r] = f2b(val);
      }
      *(u16x4*)&R0[v][col * 128 + SWZ(m0 + l4 * 4, col)] = pk;
    }
  }
  __syncthreads();  // B2: adj complete (both)

  bf16x8 afj[2][4];
#pragma unroll
  for (int v = 0; v < 2; ++v)
#pragma unroll
    for (int ks = 0; ks < 4; ++ks)
      afj[v][ks] = *(const bf16x8*)&R0[v][(m0 + l15) * 128 + SWZ(ks * 32 + l4 * 8, m0 + l15)];
  // afj/op1 writes touch only this wave's own rows -> no barrier (R12-proven)

  // ---- op1: h1 = leaky(adj @ XW1b + b1), interleaved per nt, B prefetched ----
  const unsigned short* XWb0 = XW1T + (size_t)bb[0] * 256 * 128;
  const unsigned short* XWb1 = XW1T + (size_t)bb[1] * 256 * 128;
#pragma unroll 1
  for (int half = 0; half < 2; ++half) {
    const unsigned short* Bb0 = XWb0 + (size_t)half * 128 * 128 + l4 * 8;
    const unsigned short* Bb1 = XWb1 + (size_t)half * 128 * 128 + l4 * 8;
    bf16x8 bpf[2][4];
#pragma unroll
    for (int ks = 0; ks < 4; ++ks) {
      bpf[0][ks] = *(const bf16x8*)&Bb0[(size_t)l15 * 128 + ks * 32];
      bpf[1][ks] = *(const bf16x8*)&Bb1[(size_t)l15 * 128 + ks * 32];
    }
#pragma unroll 1
    for (int nt = 0; nt < 8; ++nt) {
      float bias = b1g[half * 128 + nt * 16 + l15];
#pragma unroll
      for (int v = 0; v < 2; ++v) {
        bf16x8 bc[4];
#pragma unroll
        for (int ks = 0; ks < 4; ++ks) bc[ks] = bpf[v][ks];
        if (nt < 7) {
          const unsigned short* Bn = (v ? Bb1 : Bb0) + (size_t)((nt + 1) * 16 + l15) * 128;
#pragma unroll
          for (int ks = 0; ks < 4; ++ks) bpf[v][ks] = *(const bf16x8*)&Bn[ks * 32];
        }
        f32x4 acc = {};
#pragma unroll
        for (int ks = 0; ks < 4; ++ks)
          acc = __builtin_amdgcn_mfma_f32_16x16x32_bf16(afj[v][ks], bc[ks], acc, 0, 0, 0);
        unsigned short* Rd = half ? R0[v] : R1[v];
#pragma unroll
        for (int r = 0; r < 4; ++r) {
          int row = m0 + l4 * 4 + r;
          Rd[row * 128 + SWZ(nt * 16 + l15, row)] = f2b(leaky(acc[r] + bias));
        }
      }
    }
  }
  __syncthreads();  // B3: h1 complete (both)

  // ---- op2: u2T = W2T @ h1^T, K=256; A shared + prefetched 1 ks ahead ----
  f32x4 u2[2][2][8] = {};
  {
    const unsigned short* A0 = &W2T[(size_t)(w * 32 + l15) * 256 + l4 * 8];
    const unsigned short* A1 = &W2T[(size_t)(w * 32 + 16 + l15) * 256 + l4 * 8];
    bf16x8 a0p = *(const bf16x8*)&A0[0];
    bf16x8 a1p = *(const bf16x8*)&A1[0];
#pragma unroll 1
    for (int ks = 0; ks < 8; ++ks) {
      bf16x8 a0 = a0p, a1 = a1p;
      if (ks < 7) {
        a0p = *(const bf16x8*)&A0[(ks + 1) * 32];
        a1p = *(const bf16x8*)&A1[(ks + 1) * 32];
      }
      int kk = (ks & 3) * 32 + l4 * 8;
#pragma unroll
      for (int v = 0; v < 2; ++v) {
        const unsigned short* Rs = (ks < 4) ? R1[v] : R0[v];
#pragma unroll
        for (int nt = 0; nt < 8; ++nt) {
          int br = nt * 16 + l15;
          bf16x8 bf = *(const bf16x8*)&Rs[br * 128 + SWZ(kk, br)];
          u2[v][0][nt] = __builtin_amdgcn_mfma_f32_16x16x32_bf16(a0, bf, u2[v][0][nt], 0, 0, 0);
          u2[v][1][nt] = __builtin_amdgcn_mfma_f32_16x16x32_bf16(a1, bf, u2[v][1][nt], 0, 0, 0);
        }
      }
    }
  }
  __syncthreads();  // B4: h1 reads done (both)

#pragma unroll
  for (int v = 0; v < 2; ++v)
#pragma unroll
    for (int mt = 0; mt < 2; ++mt)
#pragma unroll
      for (int nt = 0; nt < 8; ++nt)
#pragma unroll
        for (int r = 0; r < 4; ++r) {
          int grow = w * 32 + mt * 16 + l4 * 4 + r;
          int col = nt * 16 + l15;
          unsigned short* Rd = (grow < 128) ? R0[v] : R1[v];
          int lr = grow & 127;
          Rd[lr * 128 + SWZ(col, lr)] = f2b(u2[v][mt][nt][r]);
        }
  __syncthreads();  // B5: u2T stored

  // ---- op3: h2 = leaky(adj @ u2 + b2), full hid 256, interleaved ----
  f32x4 h2[2][16];
#pragma unroll
  for (int v = 0; v < 2; ++v)
#pragma unroll
    for (int nt = 0; nt < 16; ++nt) h2[v][nt] = f32x4{0.f, 0.f, 0.f, 0.f};
#pragma unroll
  for (int ks = 0; ks < 4; ++ks)
#pragma unroll
    for (int nt = 0; nt < 16; ++nt) {
      int brl = (nt & 7) * 16 + l15;
#pragma unroll
      for (int v = 0; v < 2; ++v) {
        const unsigned short* Rs = (nt < 8) ? R0[v] : R1[v];
        bf16x8 bf = *(const bf16x8*)&Rs[brl * 128 + SWZ(ks * 32 + l4 * 8, brl)];
        h2[v][nt] = __builtin_amdgcn_mfma_f32_16x16x32_bf16(afj[v][ks], bf, h2[v][nt], 0, 0, 0);
      }
    }
  __syncthreads();  // B6: u2T reads done

#pragma unroll
  for (int v = 0; v < 2; ++v)
#pragma unroll
    for (int nt = 0; nt < 16; ++nt) {
      float bias = b2g[nt * 16 + l15];
#pragma unroll
      for (int r = 0; r < 4; ++r) {
        int row = m0 + l4 * 4 + r;
        int coll = (nt & 7) * 16 + l15;
        unsigned short* Rd = (nt < 8) ? R0[v] : R1[v];
        Rd[row * 128 + SWZ(coll, row)] = f2b(leaky(h2[v][nt][r] + bias));
      }
    }
  // ---- hoist op4 A-frags (shared across pair) ----
  const int mrow = (w >> 1) * 16, ntb = (w & 1) * 4;
  bf16x8 a3f[8];
#pragma unroll
  for (int ks = 0; ks < 8; ++ks)
    a3f[ks] = *(const bf16x8*)&W3T[(size_t)(mrow + l15) * 256 + ks * 32 + l4 * 8];
  __syncthreads();  // B7: h2 stored

  // ---- op4: u3T = W3T @ h2^T, K=256, interleaved ----
  f32x4 u3[2][4] = {};
#pragma unroll
  for (int kh = 0; kh < 2; ++kh) {
#pragma unroll
    for (int ks = 0; ks < 4; ++ks) {
#pragma unroll
      for (int nti = 0; nti < 4; ++nti) {
        int br = (ntb + nti) * 16 + l15;
#pragma unroll
        for (int v = 0; v < 2; ++v) {
          const unsigned short* Rs = kh ? R1[v] : R0[v];
          bf16x8 bf = *(const bf16x8*)&Rs[br * 128 + SWZ(ks * 32 + l4 * 8, br)];
          u3[v][nti] = __builtin_amdgcn_mfma_f32_16x16x32_bf16(a3f[kh * 4 + ks], bf, u3[v][nti], 0, 0, 0);
        }
      }
    }
  }
  __syncthreads();  // B8: h2 reads done

#pragma unroll
  for (int v = 0; v < 2; ++v)
#pragma unroll
    for (int nti = 0; nti < 4; ++nti)
#pragma unroll
      for (int r = 0; r < 4; ++r) {
        int grow = mrow + l4 * 4 + r;
        int col = (ntb + nti) * 16 + l15;
        R0[v][grow * 128 + SWZ(col, grow)] = f2b(u3[v][nti][r]);
      }
  __syncthreads();  // B9: u3T stored

  // ---- op5: xa = leaky(adj @ u3 + b3); mean via shuffles, interleaved ----
#pragma unroll 1
  for (int nt = 0; nt < 4; ++nt) {
    int br = nt * 16 + l15;
    float bias = b3g[br];
#pragma unroll
    for (int v = 0; v < 2; ++v) {
      f32x4 acc = {};
#pragma unroll
      for (int ks = 0; ks < 4; ++ks) {
        bf16x8 bf = *(const bf16x8*)&R0[v][br * 128 + SWZ(ks * 32 + l4 * 8, br)];
        acc = __builtin_amdgcn_mfma_f32_16x16x32_bf16(afj[v][ks], bf, acc, 0, 0, 0);
      }
      float s = 0.f;
#pragma unroll
      for (int r = 0; r < 4; ++r) s += leaky(acc[r] + bias);
      s += __shfl_xor(s, 16);
      s += __shfl_xor(s, 32);
      if (l4 == 0) reinterpret_cast<float*>(R1[v])[w * 64 + br] = s;
    }
  }
  __syncthreads();  // B10
  if (tid < 128) {
    int v = tid >> 6, c = tid & 63;
    const float* pf = reinterpret_cast<const float*>(R1[v]);
    float s = 0.f;
#pragma unroll
    for (int gg = 0; gg < 8; ++gg) s += pf[gg * 64 + c];
    gXa[((size_t)bb[v] * 15 + aa[v]) * 64 + c] = s * inv128;
  }
}

// ---------------- k_head: per-batch head ----------------
__global__ __launch_bounds__(256) void k_head(const float* __restrict__ gXa,
                                              const float* __restrict__ W4,
                                              const float* __restrict__ b4,
                                              float* __restrict__ out) {
  __shared__ float xb[15 * 64];
  __shared__ float c2[15 * 16];
  __shared__ float mu[15];
  __shared__ float dinv[15];
  __shared__ float yy[15 * 64];
  __shared__ float zz[15 * 64];
  const int b = blockIdx.x;
  const int tid = threadIdx.x;
  for (int e = tid; e < 960; e += 256) xb[e] = gXa[(size_t)b * 960 + e];
  __syncthreads();
  if (tid < 15) {
    float s = 0.f;
    for (int c = 0; c < 64; ++c) s += xb[tid * 64 + c];
    mu[tid] = s * (1.f / 64.f);
  }
  __syncthreads();
  if (tid < 225) {
    int p = tid / 15, q = tid % 15;
    float s = 0.f;
    for (int c = 0; c < 64; ++c)
      s += (xb[p * 64 + c] - mu[p]) * (xb[q * 64 + c] - mu[q]);
    c2[p * 16 + q] = s;
  }
  __syncthreads();
  if (tid < 15) {
    float d = c2[tid * 16 + tid];
    dinv[tid] = d > 0.f ? (1.f / sqrtf(d)) : 0.f;
  }
  __syncthreads();
  if (tid < 225) {
    int p = tid / 15, q = tid % 15;
    float v = c2[p * 16 + q] * dinv[p] * dinv[q];
    v = fminf(1.f, fmaxf(-1.f, v));
    if (dinv[p] == 0.f || dinv[q] == 0.f) v = 0.f;
    c2[p * 16 + q] = v;
  }
  __syncthreads();
  for (int e = tid; e < 960; e += 256) {
    int p = e >> 6, c = e & 63;
    float s = 0.f;
    for (int q = 0; q < 15; ++q) s += c2[p * 16 + q] * xb[q * 64 + c];
    yy[e] = s;
  }
  __syncthreads();
  for (int e = tid; e < 960; e += 256) {
    int p = e >> 6, c = e & 63;
    float s = b4[c];
    for (int k = 0; k < 64; ++k) s += yy[p * 64 + k] * W4[k * 64 + c];
    zz[e] = leaky(s);
  }
  __syncthreads();
  if (tid < 64) {
    float m = -INFINITY;
    for (int p = 0; p < 15; ++p) m = fmaxf(m, zz[p * 64 + tid]);
    out[(size_t)b * 64 + tid] = m;
  }
}

extern "C" void kernel_launch(void* const* d_in, const int* in_sizes, int n_in,
                              void* d_out, int out_size, void* d_ws, size_t ws_size,
                              hipStream_t stream) {
  const float* x  = (const float*)d_in[0];
  const float* W1 = (const float*)d_in[1];
  const float* b1 = (const float*)d_in[2];
  const float* W2 = (const float*)d_in[3];
  const float* b2 = (const float*)d_in[4];
  const float* W3 = (const float*)d_in[5];
  const float* b3 = (const float*)d_in[6];
  const float* W4 = (const float*)d_in[7];
  const float* b4 = (const float*)d_in[8];
  float* out = (float*)d_out;

  char* ws = (char*)d_ws;
  unsigned short* xT   = (unsigned short*)ws;                 // 16 MB
  unsigned short* XW1T = (unsigned short*)(ws + 16777216);    // 2 MB
  unsigned short* W2T  = (unsigned short*)(ws + 18874368);    // 128 KB
  unsigned short* W3T  = (unsigned short*)(ws + 19005440);    // 32 KB
  float* gXa           = (float*)(ws + 19038208);             // 120 KB

  k_front<<<2324, 512, 0, stream>>>(x, W1, W2, W3, W2T, W3T, xT, XW1T);
  k_chain<<<240, 512, 0, stream>>>(xT, XW1T, W2T, W3T, b1, b2, b3, gXa);
  k_head<<<32, 256, 0, stream>>>(gXa, W4, b4, out);
}